// Round 2
// baseline (911.165 us; speedup 1.0000x reference)
//
#include <hip/hip_runtime.h>

// ProportionalAttentionWrapper on MI355X (gfx950), fp16 MFMA pipeline (fp32 accum).
// B=2, S=4096, C=1024, H=16, DH=64. out = softmax(QK^T * 64^0.25 + log(ts)) V, proj.
// fp16 internal precision (8x finer mantissa than bf16) keeps absmax ~8x under the
// 9*bf16-eps threshold at identical MFMA rate.
// Workspace layout (bytes), total 75,530,240:
//   [0, 16M)            x_fp16 [8192][1024]  (reused as attn_out [B][S][C] fp16)
//   [16M, 24M)          Wt q/k/v/o fp16 [1024][1024] each (q,k,v contiguous => N=3072 GEMM)
//   [24M(25165824), +3*16M) q,k,v fp16 [B*H][S][DH] contiguous
//   [75497472, +32KB)   log(token_sizes) fp32 [B][S]

typedef unsigned short u16;
typedef unsigned int u32;
typedef _Float16 f16x8 __attribute__((ext_vector_type(8)));
typedef float f32x4 __attribute__((ext_vector_type(4)));
typedef short short4v __attribute__((ext_vector_type(4)));

constexpr int SEQ = 4096, CDIM = 1024, NH = 16, DHE = 64;
constexpr float SCALEF = 2.8284271247461903f;  // 64^0.25

union Frag { f16x8 v; short4v h[2]; };

__device__ __forceinline__ u16 f2h(float f) {
  union { _Float16 h; u16 u; } x;
  x.h = (_Float16)f;  // v_cvt_f16_f32, RNE
  return x.u;
}

__device__ __forceinline__ f32x4 mfma16(const Frag& a, const Frag& b, f32x4 c) {
  return __builtin_amdgcn_mfma_f32_16x16x32_f16(a.v, b.v, c, 0, 0, 0);
}

// ---- prep kernels -----------------------------------------------------------

__global__ void cast_x_kernel(const float* __restrict__ x, u16* __restrict__ out) {
  size_t i = ((size_t)blockIdx.x * 256 + threadIdx.x) * 8;
  float4 a = *(const float4*)(x + i);
  float4 b = *(const float4*)(x + i + 4);
  uint4 o;
  o.x = (u32)f2h(a.x) | ((u32)f2h(a.y) << 16);
  o.y = (u32)f2h(a.z) | ((u32)f2h(a.w) << 16);
  o.z = (u32)f2h(b.x) | ((u32)f2h(b.y) << 16);
  o.w = (u32)f2h(b.z) | ((u32)f2h(b.w) << 16);
  *(uint4*)(out + i) = o;
}

__global__ void transpose_w_kernel(const float* __restrict__ w, u16* __restrict__ wt) {
  int idx = blockIdx.x * 256 + threadIdx.x;  // idx = n*1024 + k
  int n = idx >> 10, k = idx & 1023;
  wt[idx] = f2h(w[k * 1024 + n]);
}

__global__ void logsz_kernel(const int* __restrict__ ts, float* __restrict__ out) {
  int i = blockIdx.x * 256 + threadIdx.x;
  out[i] = logf((float)ts[i]);
}

// ---- GEMM: C[M,N] = A[M,K] * Bt[N,K]^T, M=8192, K=1024 ----------------------
// EPI=0: N=3072, write fp16 to q/k/v [which][B*H][S][DH]; EPI=1: N=1024, fp32 out + bias.

template <int EPI>
__global__ __launch_bounds__(256) void gemm_f16(const u16* __restrict__ A,
                                                const u16* __restrict__ Bt,
                                                void* __restrict__ Out,
                                                const float* __restrict__ bias) {
  __shared__ __align__(16) short Alds[128][40];
  __shared__ __align__(16) short Blds[128][40];
  const int t = threadIdx.x;
  const int bnb = blockIdx.x;   // N/128 blocks
  const int bm = blockIdx.y;    // 64
  const int lane = t & 63, wv = t >> 6;
  const int wm = wv >> 1, wn = wv & 1;
  const int l16 = lane & 15, lq = lane >> 4;

  f32x4 acc[4][4];
  f32x4 z = {0.f, 0.f, 0.f, 0.f};
#pragma unroll
  for (int i = 0; i < 4; ++i)
#pragma unroll
    for (int j = 0; j < 4; ++j) acc[i][j] = z;

  const int srow = (t * 8) >> 5;  // staging: 0..63 (+64 on 2nd pass)
  const int scol = (t * 8) & 31;

  for (int kb = 0; kb < 32; ++kb) {
    const int k0 = kb * 32;
#pragma unroll
    for (int i = 0; i < 2; ++i) {
      const int row = srow + i * 64;
      uint4 va = *(const uint4*)(A + (size_t)(bm * 128 + row) * 1024 + k0 + scol);
      *(uint4*)&Alds[row][scol] = va;
      uint4 vb = *(const uint4*)(Bt + (size_t)(bnb * 128 + row) * 1024 + k0 + scol);
      *(uint4*)&Blds[row][scol] = vb;
    }
    __syncthreads();

    Frag af[4], bf[4];
#pragma unroll
    for (int am = 0; am < 4; ++am) {
      const short* p = &Alds[wm * 64 + am * 16 + l16][lq * 4];
      af[am].h[0] = *(const short4v*)p;
      af[am].h[1] = *(const short4v*)(p + 16);
    }
#pragma unroll
    for (int bn = 0; bn < 4; ++bn) {
      const short* p = &Blds[wn * 64 + bn * 16 + l16][lq * 4];
      bf[bn].h[0] = *(const short4v*)p;
      bf[bn].h[1] = *(const short4v*)(p + 16);
    }
#pragma unroll
    for (int am = 0; am < 4; ++am)
#pragma unroll
      for (int bn = 0; bn < 4; ++bn) acc[am][bn] = mfma16(af[am], bf[bn], acc[am][bn]);
    __syncthreads();
  }

#pragma unroll
  for (int am = 0; am < 4; ++am) {
#pragma unroll
    for (int bn = 0; bn < 4; ++bn) {
#pragma unroll
      for (int r = 0; r < 4; ++r) {
        const int m = bm * 128 + wm * 64 + am * 16 + lq * 4 + r;  // D row map (HW-verified)
        const int n = bnb * 128 + wn * 64 + bn * 16 + l16;        // D col map
        const float vsum = acc[am][bn][r];
        if (EPI == 0) {
          const int which = n >> 10;           // 0=q 1=k 2=v
          const int nn = n & 1023;
          const int h = nn >> 6, d = nn & 63;
          const int b = m >> 12, s = m & 4095;
          ((u16*)Out)[(size_t)which * 8388608 +
                      (((size_t)(b * NH + h)) * SEQ + s) * DHE + d] = f2h(vsum);
        } else {
          ((float*)Out)[(size_t)m * 1024 + n] = vsum + bias[n];
        }
      }
    }
  }
}

// ---- flash attention --------------------------------------------------------
// grid: bh*64 + qb. 4 waves x 16 q-rows = 64 q-rows/block, KBLK=64.

__global__ __launch_bounds__(256) void attn_kernel(const u16* __restrict__ Q,
                                                   const u16* __restrict__ K,
                                                   const u16* __restrict__ V,
                                                   const float* __restrict__ logsz,
                                                   u16* __restrict__ Out) {
  __shared__ __align__(16) short Klds[64][72];
  __shared__ __align__(16) short Vtlds[64][72];   // [d][key]
  __shared__ __align__(16) short Plds[4][16][72];

  const int t = threadIdx.x;
  const int bh = blockIdx.x >> 6;
  const int qb = blockIdx.x & 63;
  const int lane = t & 63, wv = t >> 6;
  const int l16 = lane & 15, lq = lane >> 4;
  const int b = bh >> 4, h = bh & 15;

  // Q fragments (A operand, row = l16)
  Frag qf[2];
  {
    const int qrow = qb * 64 + wv * 16 + l16;
    const u16* qp = Q + ((size_t)bh * SEQ + qrow) * DHE;
#pragma unroll
    for (int f = 0; f < 2; ++f) {
      qf[f].h[0] = *(const short4v*)(qp + f * 32 + lq * 4);
      qf[f].h[1] = *(const short4v*)(qp + f * 32 + lq * 4 + 16);
    }
  }

  float mrow[4], lrow[4];
  f32x4 oacc[4];
  f32x4 z = {0.f, 0.f, 0.f, 0.f};
#pragma unroll
  for (int r = 0; r < 4; ++r) { mrow[r] = -1e30f; lrow[r] = 0.f; }
#pragma unroll
  for (int d = 0; d < 4; ++d) oacc[d] = z;

  const int skey = t >> 3;        // 0..31 (+32 on 2nd pass)
  const int sd = (t & 7) * 8;

  for (int kt = 0; kt < 64; ++kt) {
    // stage K[64][64] row-major and V transposed -> Vt[d][key]
#pragma unroll
    for (int i = 0; i < 2; ++i) {
      const int key = skey + i * 32;
      const size_t gb = ((size_t)bh * SEQ + kt * 64 + key) * DHE + sd;
      uint4 kv = *(const uint4*)(K + gb);
      *(uint4*)&Klds[key][sd] = kv;
      uint4 vv = *(const uint4*)(V + gb);
      u16 vu[8];
      *(uint4*)vu = vv;
#pragma unroll
      for (int j = 0; j < 8; ++j) Vtlds[sd + j][key] = (short)vu[j];
    }
    __syncthreads();

    // S = Q K^T  (16 q-rows x 64 keys per wave)
    f32x4 sc[4];
#pragma unroll
    for (int k2 = 0; k2 < 4; ++k2) {
      f32x4 a = z;
#pragma unroll
      for (int f = 0; f < 2; ++f) {
        Frag kfr;
        const short* p = &Klds[k2 * 16 + l16][f * 32 + lq * 4];
        kfr.h[0] = *(const short4v*)p;
        kfr.h[1] = *(const short4v*)(p + 16);
        a = mfma16(qf[f], kfr, a);
      }
      sc[k2] = a;
    }

    float lg[4];
#pragma unroll
    for (int k2 = 0; k2 < 4; ++k2) lg[k2] = logsz[b * SEQ + kt * 64 + k2 * 16 + l16];

    float alpha[4];
#pragma unroll
    for (int r = 0; r < 4; ++r) {
      float v0 = -1e30f;
#pragma unroll
      for (int k2 = 0; k2 < 4; ++k2) {
        float s = sc[k2][r] * SCALEF + lg[k2];
        sc[k2][r] = s;
        v0 = fmaxf(v0, s);
      }
#pragma unroll
      for (int mm = 1; mm < 16; mm <<= 1) v0 = fmaxf(v0, __shfl_xor(v0, mm));
      const float mn = fmaxf(mrow[r], v0);
      alpha[r] = __expf(mrow[r] - mn);
      mrow[r] = mn;
    }
#pragma unroll
    for (int r = 0; r < 4; ++r) {
      float rs = 0.f;
#pragma unroll
      for (int k2 = 0; k2 < 4; ++k2) {
        float p = __expf(sc[k2][r] - mrow[r]);
        sc[k2][r] = p;
        rs += p;
      }
#pragma unroll
      for (int mm = 1; mm < 16; mm <<= 1) rs += __shfl_xor(rs, mm);
      lrow[r] = lrow[r] * alpha[r] + rs;
    }
#pragma unroll
    for (int d = 0; d < 4; ++d)
#pragma unroll
      for (int r = 0; r < 4; ++r) oacc[d][r] *= alpha[r];

    // P -> LDS (per-wave region; wave-internal ordering via lgkmcnt)
#pragma unroll
    for (int k2 = 0; k2 < 4; ++k2)
#pragma unroll
      for (int r = 0; r < 4; ++r)
        Plds[wv][lq * 4 + r][k2 * 16 + l16] = (short)f2h(sc[k2][r]);

    // O += P V
#pragma unroll
    for (int kh = 0; kh < 2; ++kh) {
      Frag pa;
      const short* pp = &Plds[wv][l16][kh * 32 + lq * 4];
      pa.h[0] = *(const short4v*)pp;
      pa.h[1] = *(const short4v*)(pp + 16);
#pragma unroll
      for (int d = 0; d < 4; ++d) {
        Frag vb;
        const short* vp = &Vtlds[d * 16 + l16][kh * 32 + lq * 4];
        vb.h[0] = *(const short4v*)vp;
        vb.h[1] = *(const short4v*)(vp + 16);
        oacc[d] = mfma16(pa, vb, oacc[d]);
      }
    }
    __syncthreads();
  }

  // write attn output merged-head [B][S][C] fp16
#pragma unroll
  for (int d = 0; d < 4; ++d) {
#pragma unroll
    for (int r = 0; r < 4; ++r) {
      const int row = qb * 64 + wv * 16 + lq * 4 + r;
      const float v = oacc[d][r] / lrow[r];
      Out[((size_t)b * SEQ + row) * CDIM + h * DHE + d * 16 + l16] = f2h(v);
    }
  }
}

// ---- launcher ---------------------------------------------------------------

extern "C" void kernel_launch(void* const* d_in, const int* in_sizes, int n_in,
                              void* d_out, int out_size, void* d_ws, size_t ws_size,
                              hipStream_t stream) {
  const float* hs = (const float*)d_in[0];
  const float* Wq = (const float*)d_in[1];
  const float* Wk = (const float*)d_in[2];
  const float* Wv = (const float*)d_in[3];
  const float* Wo = (const float*)d_in[4];
  const float* bo = (const float*)d_in[5];
  const int* ts = (const int*)d_in[6];
  float* out = (float*)d_out;

  char* ws = (char*)d_ws;
  u16* xf = (u16*)(ws);                     // 16,777,216 B; reused as attn_out
  u16* wtq = (u16*)(ws + 16777216);         // q/k/v Wt contiguous -> one N=3072 GEMM
  u16* wtk = (u16*)(ws + 18874368);
  u16* wtv = (u16*)(ws + 20971520);
  u16* wto = (u16*)(ws + 23068672);
  u16* qbuf = (u16*)(ws + 25165824);        // q,k,v contiguous (8,388,608 elems each)
  u16* kbuf = (u16*)(ws + 41943040);
  u16* vbuf = (u16*)(ws + 58720256);
  float* lsz = (float*)(ws + 75497472);

  cast_x_kernel<<<4096, 256, 0, stream>>>(hs, xf);
  transpose_w_kernel<<<4096, 256, 0, stream>>>(Wq, wtq);
  transpose_w_kernel<<<4096, 256, 0, stream>>>(Wk, wtk);
  transpose_w_kernel<<<4096, 256, 0, stream>>>(Wv, wtv);
  transpose_w_kernel<<<4096, 256, 0, stream>>>(Wo, wto);
  logsz_kernel<<<32, 256, 0, stream>>>(ts, lsz);

  // fused QKV projection: A[8192,1024] x Bt[3072,1024]^T
  gemm_f16<0><<<dim3(24, 64), 256, 0, stream>>>(xf, wtq, (void*)qbuf, nullptr);

  attn_kernel<<<2048, 256, 0, stream>>>(qbuf, kbuf, vbuf, lsz, xf);

  // output projection + bias
  gemm_f16<1><<<dim3(8, 64), 256, 0, stream>>>(xf, wto, (void*)out, bo);

  (void)in_sizes; (void)n_in; (void)out_size; (void)ws_size;
}

// Round 3
// 547.635 us; speedup vs baseline: 1.6638x; 1.6638x over previous
//
#include <hip/hip_runtime.h>

// ProportionalAttentionWrapper on MI355X (gfx950), fp16 MFMA pipeline (fp32 accum).
// B=2, S=4096, C=1024, H=16, DH=64. out = softmax(QK^T * 64^0.25 + log(ts)) V, proj.
// Attention uses swapped QK^T (mfma(K,Q) -> P[key][q]) so P stays in registers as
// the PV A-fragment; V^T staged in LDS with XOR column swizzle (bank-conflict-free).
// Workspace layout (bytes), total 75,530,240:
//   [0, 16M)            x_fp16 [8192][1024]  (reused as attn_out [B][S][C] fp16)
//   [16M, 24M)          Wt q/k/v/o fp16 [1024][1024] each (q,k,v contiguous => N=3072 GEMM)
//   [24M(25165824), +3*16M) q,k,v fp16 [B*H][S][DH] contiguous
//   [75497472, +32KB)   log(token_sizes) fp32 [B][S]

typedef unsigned short u16;
typedef unsigned int u32;
typedef _Float16 f16x8 __attribute__((ext_vector_type(8)));
typedef float f32x4 __attribute__((ext_vector_type(4)));
typedef short short4v __attribute__((ext_vector_type(4)));

constexpr int SEQ = 4096, CDIM = 1024, NH = 16, DHE = 64;
constexpr float SCALEF = 2.8284271247461903f;  // 64^0.25

union Frag { f16x8 v; short4v h[2]; };

__device__ __forceinline__ u16 f2h(float f) {
  union { _Float16 h; u16 u; } x;
  x.h = (_Float16)f;  // v_cvt_f16_f32, RNE
  return x.u;
}

__device__ __forceinline__ short4v cvt4(f32x4 v) {
  union { _Float16 h[4]; short4v s; } u;
  u.h[0] = (_Float16)v[0]; u.h[1] = (_Float16)v[1];
  u.h[2] = (_Float16)v[2]; u.h[3] = (_Float16)v[3];
  return u.s;
}

__device__ __forceinline__ f32x4 mfma16(const Frag& a, const Frag& b, f32x4 c) {
  return __builtin_amdgcn_mfma_f32_16x16x32_f16(a.v, b.v, c, 0, 0, 0);
}

// ---- prep kernels -----------------------------------------------------------

__global__ void cast_x_kernel(const float* __restrict__ x, u16* __restrict__ out) {
  size_t i = ((size_t)blockIdx.x * 256 + threadIdx.x) * 8;
  float4 a = *(const float4*)(x + i);
  float4 b = *(const float4*)(x + i + 4);
  uint4 o;
  o.x = (u32)f2h(a.x) | ((u32)f2h(a.y) << 16);
  o.y = (u32)f2h(a.z) | ((u32)f2h(a.w) << 16);
  o.z = (u32)f2h(b.x) | ((u32)f2h(b.y) << 16);
  o.w = (u32)f2h(b.z) | ((u32)f2h(b.w) << 16);
  *(uint4*)(out + i) = o;
}

__global__ void transpose_w_kernel(const float* __restrict__ w, u16* __restrict__ wt) {
  int idx = blockIdx.x * 256 + threadIdx.x;  // idx = n*1024 + k
  int n = idx >> 10, k = idx & 1023;
  wt[idx] = f2h(w[k * 1024 + n]);
}

__global__ void logsz_kernel(const int* __restrict__ ts, float* __restrict__ out) {
  int i = blockIdx.x * 256 + threadIdx.x;
  out[i] = logf((float)ts[i]);
}

// ---- GEMM: C[M,N] = A[M,K] * Bt[N,K]^T, M=8192, K=1024 ----------------------
// EPI=0: N=3072, write fp16 to q/k/v [which][B*H][S][DH]; EPI=1: N=1024, fp32 out + bias.

template <int EPI>
__global__ __launch_bounds__(256) void gemm_f16(const u16* __restrict__ A,
                                                const u16* __restrict__ Bt,
                                                void* __restrict__ Out,
                                                const float* __restrict__ bias) {
  __shared__ __align__(16) short Alds[128][40];
  __shared__ __align__(16) short Blds[128][40];
  const int t = threadIdx.x;
  const int bnb = blockIdx.x;   // N/128 blocks
  const int bm = blockIdx.y;    // 64
  const int lane = t & 63, wv = t >> 6;
  const int wm = wv >> 1, wn = wv & 1;
  const int l16 = lane & 15, lq = lane >> 4;

  f32x4 acc[4][4];
  f32x4 z = {0.f, 0.f, 0.f, 0.f};
#pragma unroll
  for (int i = 0; i < 4; ++i)
#pragma unroll
    for (int j = 0; j < 4; ++j) acc[i][j] = z;

  const int srow = (t * 8) >> 5;  // staging: 0..63 (+64 on 2nd pass)
  const int scol = (t * 8) & 31;

  for (int kb = 0; kb < 32; ++kb) {
    const int k0 = kb * 32;
#pragma unroll
    for (int i = 0; i < 2; ++i) {
      const int row = srow + i * 64;
      uint4 va = *(const uint4*)(A + (size_t)(bm * 128 + row) * 1024 + k0 + scol);
      *(uint4*)&Alds[row][scol] = va;
      uint4 vb = *(const uint4*)(Bt + (size_t)(bnb * 128 + row) * 1024 + k0 + scol);
      *(uint4*)&Blds[row][scol] = vb;
    }
    __syncthreads();

    Frag af[4], bf[4];
#pragma unroll
    for (int am = 0; am < 4; ++am) {
      const short* p = &Alds[wm * 64 + am * 16 + l16][lq * 4];
      af[am].h[0] = *(const short4v*)p;
      af[am].h[1] = *(const short4v*)(p + 16);
    }
#pragma unroll
    for (int bn = 0; bn < 4; ++bn) {
      const short* p = &Blds[wn * 64 + bn * 16 + l16][lq * 4];
      bf[bn].h[0] = *(const short4v*)p;
      bf[bn].h[1] = *(const short4v*)(p + 16);
    }
#pragma unroll
    for (int am = 0; am < 4; ++am)
#pragma unroll
      for (int bn = 0; bn < 4; ++bn) acc[am][bn] = mfma16(af[am], bf[bn], acc[am][bn]);
    __syncthreads();
  }

#pragma unroll
  for (int am = 0; am < 4; ++am) {
#pragma unroll
    for (int bn = 0; bn < 4; ++bn) {
#pragma unroll
      for (int r = 0; r < 4; ++r) {
        const int m = bm * 128 + wm * 64 + am * 16 + lq * 4 + r;  // D row map (HW-verified)
        const int n = bnb * 128 + wn * 64 + bn * 16 + l16;        // D col map
        const float vsum = acc[am][bn][r];
        if (EPI == 0) {
          const int which = n >> 10;           // 0=q 1=k 2=v
          const int nn = n & 1023;
          const int h = nn >> 6, d = nn & 63;
          const int b = m >> 12, s = m & 4095;
          ((u16*)Out)[(size_t)which * 8388608 +
                      (((size_t)(b * NH + h)) * SEQ + s) * DHE + d] = f2h(vsum);
        } else {
          ((float*)Out)[(size_t)m * 1024 + n] = vsum + bias[n];
        }
      }
    }
  }
}

// ---- flash attention --------------------------------------------------------
// grid: bh*64 + qb. 4 waves x 16 q-rows = 64 q-rows/block, KBLK=64.
// Swapped QK^T: sc = mfma(K_frag, Q_frag) -> lane(l16,lq) reg r holds
// P[key = lq*4+r (+16*k2)][q = l16]; softmax per-lane over 16 regs + 2 shfl_xor;
// P feeds PV's A operand directly (no LDS round trip).

__global__ __launch_bounds__(256) void attn_kernel(const u16* __restrict__ Q,
                                                   const u16* __restrict__ K,
                                                   const u16* __restrict__ V,
                                                   const float* __restrict__ logsz,
                                                   u16* __restrict__ Out) {
  __shared__ __align__(16) short Klds[64][72];
  __shared__ __align__(16) short Vtlds[64][72];   // [d][key ^ ((d>>3)<<3)] swizzled

  const int t = threadIdx.x;
  const int bh = blockIdx.x >> 6;
  const int qb = blockIdx.x & 63;
  const int lane = t & 63, wv = t >> 6;
  const int l16 = lane & 15, lq = lane >> 4;
  const int b = bh >> 4, h = bh & 15;

  // Q fragment (B operand for swapped QK^T; row = l16 = q_local)
  Frag qf[2];
  {
    const int qrow = qb * 64 + wv * 16 + l16;
    const u16* qp = Q + ((size_t)bh * SEQ + qrow) * DHE;
#pragma unroll
    for (int f = 0; f < 2; ++f) {
      qf[f].h[0] = *(const short4v*)(qp + f * 32 + lq * 4);
      qf[f].h[1] = *(const short4v*)(qp + f * 32 + lq * 4 + 16);
    }
  }

  float mrow = -1e30f, lrow = 0.f;   // running max/sum for q = l16 (this lane's column)
  f32x4 oacc[4];
  f32x4 z = {0.f, 0.f, 0.f, 0.f};
#pragma unroll
  for (int d = 0; d < 4; ++d) oacc[d] = z;

  const int a7 = t & 7;           // staging lane geometry
  const int sd = a7 * 8;
  const int skey = t >> 3;        // 0..31 (+32 on 2nd pass)

  for (int kt = 0; kt < 64; ++kt) {
    // stage K[64][64] row-major; V transposed -> Vt[d][key ^ (a7<<3)] (swizzled)
#pragma unroll
    for (int i = 0; i < 2; ++i) {
      const int key = skey + i * 32;
      const size_t gb = ((size_t)bh * SEQ + kt * 64 + key) * DHE + sd;
      uint4 kv = *(const uint4*)(K + gb);
      *(uint4*)&Klds[key][sd] = kv;
      uint4 vv = *(const uint4*)(V + gb);
      u16 vu[8];
      *(uint4*)vu = vv;
      const int vcol = key ^ (a7 << 3);
#pragma unroll
      for (int j = 0; j < 8; ++j) Vtlds[sd + j][vcol] = (short)vu[j];
    }
    __syncthreads();

    // S^T = K Q^T : sc[k2] reg r = S[key = k2*16+lq*4+r][q = l16]
    f32x4 sc[4];
#pragma unroll
    for (int k2 = 0; k2 < 4; ++k2) {
      f32x4 a = z;
#pragma unroll
      for (int f = 0; f < 2; ++f) {
        Frag kfr;
        const short* p = &Klds[k2 * 16 + l16][f * 32 + lq * 4];
        kfr.h[0] = *(const short4v*)p;
        kfr.h[1] = *(const short4v*)(p + 16);
        a = mfma16(kfr, qf[f], a);
      }
      sc[k2] = a;
    }

    // scale + log-size bias (key-indexed -> vector float4 loads)
    float v0 = -1e30f;
#pragma unroll
    for (int k2 = 0; k2 < 4; ++k2) {
      float4 lg = *(const float4*)(logsz + b * SEQ + kt * 64 + k2 * 16 + lq * 4);
#pragma unroll
      for (int r = 0; r < 4; ++r) {
        float s = fmaf(sc[k2][r], SCALEF, ((const float*)&lg)[r]);
        sc[k2][r] = s;
        v0 = fmaxf(v0, s);
      }
    }
    // reduce over the 4 lanes sharing q = l16 (lq in {0..3} -> xor 16, 32)
    v0 = fmaxf(v0, __shfl_xor(v0, 16));
    v0 = fmaxf(v0, __shfl_xor(v0, 32));
    const float mn = fmaxf(mrow, v0);
    const float alpha = __expf(mrow - mn);
    mrow = mn;

    float rs = 0.f;
#pragma unroll
    for (int k2 = 0; k2 < 4; ++k2)
#pragma unroll
      for (int r = 0; r < 4; ++r) {
        float p = __expf(sc[k2][r] - mn);
        sc[k2][r] = p;
        rs += p;
      }
    rs += __shfl_xor(rs, 16);
    rs += __shfl_xor(rs, 32);
    lrow = lrow * alpha + rs;

    // redistribute alpha to output-row owners (output row q = lq*4+r)
    float al[4];
#pragma unroll
    for (int r = 0; r < 4; ++r) al[r] = __shfl(alpha, lq * 4 + r, 16);
#pragma unroll
    for (int d = 0; d < 4; ++d)
#pragma unroll
      for (int r = 0; r < 4; ++r) oacc[d][r] *= al[r];

    // P -> fp16 A-fragments (register-direct, layout matches A operand exactly)
    Frag paf[2];
    paf[0].h[0] = cvt4(sc[0]); paf[0].h[1] = cvt4(sc[1]);
    paf[1].h[0] = cvt4(sc[2]); paf[1].h[1] = cvt4(sc[3]);

    // O += P V  (Vt read with matching XOR swizzle)
#pragma unroll
    for (int dd = 0; dd < 4; ++dd) {
      const int vrow = dd * 16 + l16;
      const int e = ((vrow >> 3) & 7) << 3;
#pragma unroll
      for (int kh = 0; kh < 2; ++kh) {
        Frag vb;
        vb.h[0] = *(const short4v*)&Vtlds[vrow][(kh * 32 + lq * 4) ^ e];
        vb.h[1] = *(const short4v*)&Vtlds[vrow][(kh * 32 + 16 + lq * 4) ^ e];
        oacc[dd] = mfma16(paf[kh], vb, oacc[dd]);
      }
    }
    __syncthreads();
  }

  // write attn output merged-head [B][S][C] fp16; output row q = lq*4+r needs
  // lrow from lane (lq*4+r) of its 16-lane group
  float linv[4];
#pragma unroll
  for (int r = 0; r < 4; ++r) linv[r] = 1.f / __shfl(lrow, lq * 4 + r, 16);
#pragma unroll
  for (int dd = 0; dd < 4; ++dd) {
#pragma unroll
    for (int r = 0; r < 4; ++r) {
      const int row = qb * 64 + wv * 16 + lq * 4 + r;
      const float v = oacc[dd][r] * linv[r];
      Out[((size_t)b * SEQ + row) * CDIM + h * DHE + dd * 16 + l16] = f2h(v);
    }
  }
}

// ---- launcher ---------------------------------------------------------------

extern "C" void kernel_launch(void* const* d_in, const int* in_sizes, int n_in,
                              void* d_out, int out_size, void* d_ws, size_t ws_size,
                              hipStream_t stream) {
  const float* hs = (const float*)d_in[0];
  const float* Wq = (const float*)d_in[1];
  const float* Wk = (const float*)d_in[2];
  const float* Wv = (const float*)d_in[3];
  const float* Wo = (const float*)d_in[4];
  const float* bo = (const float*)d_in[5];
  const int* ts = (const int*)d_in[6];
  float* out = (float*)d_out;

  char* ws = (char*)d_ws;
  u16* xf = (u16*)(ws);                     // 16,777,216 B; reused as attn_out
  u16* wtq = (u16*)(ws + 16777216);         // q/k/v Wt contiguous -> one N=3072 GEMM
  u16* wtk = (u16*)(ws + 18874368);
  u16* wtv = (u16*)(ws + 20971520);
  u16* wto = (u16*)(ws + 23068672);
  u16* qbuf = (u16*)(ws + 25165824);        // q,k,v contiguous (8,388,608 elems each)
  u16* kbuf = (u16*)(ws + 41943040);
  u16* vbuf = (u16*)(ws + 58720256);
  float* lsz = (float*)(ws + 75497472);

  cast_x_kernel<<<4096, 256, 0, stream>>>(hs, xf);
  transpose_w_kernel<<<4096, 256, 0, stream>>>(Wq, wtq);
  transpose_w_kernel<<<4096, 256, 0, stream>>>(Wk, wtk);
  transpose_w_kernel<<<4096, 256, 0, stream>>>(Wv, wtv);
  transpose_w_kernel<<<4096, 256, 0, stream>>>(Wo, wto);
  logsz_kernel<<<32, 256, 0, stream>>>(ts, lsz);

  // fused QKV projection: A[8192,1024] x Bt[3072,1024]^T
  gemm_f16<0><<<dim3(24, 64), 256, 0, stream>>>(xf, wtq, (void*)qbuf, nullptr);

  attn_kernel<<<2048, 256, 0, stream>>>(qbuf, kbuf, vbuf, lsz, xf);

  // output projection + bias
  gemm_f16<1><<<dim3(8, 64), 256, 0, stream>>>(xf, wto, (void*)out, bo);

  (void)in_sizes; (void)n_in; (void)out_size; (void)ws_size;
}

// Round 4
// 404.147 us; speedup vs baseline: 2.2545x; 1.3550x over previous
//
#include <hip/hip_runtime.h>

// ProportionalAttentionWrapper on MI355X (gfx950), fp16 MFMA pipeline (fp32 accum).
// B=2, S=4096, C=1024, H=16, DH=64. out = softmax(QK^T * 64^0.25 + log(ts)) V, proj.
// Attention: swapped QK^T (P in registers), 32 q-rows/wave, exp2-domain softmax with
// deferred max (THR=8), row-sums via ones-MFMA, async-staged K/V tiles.
// Workspace layout (bytes), total 75,530,240:
//   [0, 16M)            x_fp16 [8192][1024]  (reused as attn_out [B][S][C] fp16)
//   [16M, 24M)          Wt q/k/v/o fp16 [1024][1024] each (q,k,v contiguous => N=3072 GEMM)
//   [24M(25165824), +3*16M) q,k,v fp16 [B*H][S][DH] contiguous
//   [75497472, +32KB)   log2(token_sizes) fp32 [B][S]

typedef unsigned short u16;
typedef unsigned int u32;
typedef _Float16 f16x8 __attribute__((ext_vector_type(8)));
typedef float f32x4 __attribute__((ext_vector_type(4)));
typedef short short4v __attribute__((ext_vector_type(4)));

constexpr int SEQ = 4096, CDIM = 1024, NH = 16, DHE = 64;
// 64^0.25 * log2(e): softmax runs in base-2 domain
constexpr float SCALE2 = 2.8284271247461903f * 1.4426950408889634f;

union Frag { f16x8 v; short4v h[2]; };

__device__ __forceinline__ u16 f2h(float f) {
  union { _Float16 h; u16 u; } x;
  x.h = (_Float16)f;  // v_cvt_f16_f32, RNE
  return x.u;
}

__device__ __forceinline__ short4v cvt4(f32x4 v) {
  union { _Float16 h[4]; short4v s; } u;
  u.h[0] = (_Float16)v[0]; u.h[1] = (_Float16)v[1];
  u.h[2] = (_Float16)v[2]; u.h[3] = (_Float16)v[3];
  return u.s;
}

__device__ __forceinline__ float exp2fast(float x) {
  float r;
  asm("v_exp_f32 %0, %1" : "=v"(r) : "v"(x));
  return r;
}

__device__ __forceinline__ f32x4 mfma16(const Frag& a, const Frag& b, f32x4 c) {
  return __builtin_amdgcn_mfma_f32_16x16x32_f16(a.v, b.v, c, 0, 0, 0);
}

// ---- prep kernels -----------------------------------------------------------

__global__ void cast_x_kernel(const float* __restrict__ x, u16* __restrict__ out) {
  size_t i = ((size_t)blockIdx.x * 256 + threadIdx.x) * 8;
  float4 a = *(const float4*)(x + i);
  float4 b = *(const float4*)(x + i + 4);
  uint4 o;
  o.x = (u32)f2h(a.x) | ((u32)f2h(a.y) << 16);
  o.y = (u32)f2h(a.z) | ((u32)f2h(a.w) << 16);
  o.z = (u32)f2h(b.x) | ((u32)f2h(b.y) << 16);
  o.w = (u32)f2h(b.z) | ((u32)f2h(b.w) << 16);
  *(uint4*)(out + i) = o;
}

__global__ void transpose_w_kernel(const float* __restrict__ w, u16* __restrict__ wt) {
  int idx = blockIdx.x * 256 + threadIdx.x;  // idx = n*1024 + k
  int n = idx >> 10, k = idx & 1023;
  wt[idx] = f2h(w[k * 1024 + n]);
}

__global__ void logsz_kernel(const int* __restrict__ ts, float* __restrict__ out) {
  int i = blockIdx.x * 256 + threadIdx.x;
  out[i] = log2f((float)ts[i]);   // base-2 domain bias
}

// ---- GEMM: C[M,N] = A[M,K] * Bt[N,K]^T, M=8192, K=1024 ----------------------
// EPI=0: N=3072, write fp16 to q/k/v [which][B*H][S][DH]; EPI=1: N=1024, fp32 out + bias.

template <int EPI>
__global__ __launch_bounds__(256) void gemm_f16(const u16* __restrict__ A,
                                                const u16* __restrict__ Bt,
                                                void* __restrict__ Out,
                                                const float* __restrict__ bias) {
  __shared__ __align__(16) short Alds[128][40];
  __shared__ __align__(16) short Blds[128][40];
  const int t = threadIdx.x;
  const int bnb = blockIdx.x;   // N/128 blocks
  const int bm = blockIdx.y;    // 64
  const int lane = t & 63, wv = t >> 6;
  const int wm = wv >> 1, wn = wv & 1;
  const int l16 = lane & 15, lq = lane >> 4;

  f32x4 acc[4][4];
  f32x4 z = {0.f, 0.f, 0.f, 0.f};
#pragma unroll
  for (int i = 0; i < 4; ++i)
#pragma unroll
    for (int j = 0; j < 4; ++j) acc[i][j] = z;

  const int srow = (t * 8) >> 5;  // staging: 0..63 (+64 on 2nd pass)
  const int scol = (t * 8) & 31;

  for (int kb = 0; kb < 32; ++kb) {
    const int k0 = kb * 32;
#pragma unroll
    for (int i = 0; i < 2; ++i) {
      const int row = srow + i * 64;
      uint4 va = *(const uint4*)(A + (size_t)(bm * 128 + row) * 1024 + k0 + scol);
      *(uint4*)&Alds[row][scol] = va;
      uint4 vb = *(const uint4*)(Bt + (size_t)(bnb * 128 + row) * 1024 + k0 + scol);
      *(uint4*)&Blds[row][scol] = vb;
    }
    __syncthreads();

    Frag af[4], bf[4];
#pragma unroll
    for (int am = 0; am < 4; ++am) {
      const short* p = &Alds[wm * 64 + am * 16 + l16][lq * 4];
      af[am].h[0] = *(const short4v*)p;
      af[am].h[1] = *(const short4v*)(p + 16);
    }
#pragma unroll
    for (int bn = 0; bn < 4; ++bn) {
      const short* p = &Blds[wn * 64 + bn * 16 + l16][lq * 4];
      bf[bn].h[0] = *(const short4v*)p;
      bf[bn].h[1] = *(const short4v*)(p + 16);
    }
#pragma unroll
    for (int am = 0; am < 4; ++am)
#pragma unroll
      for (int bn = 0; bn < 4; ++bn) acc[am][bn] = mfma16(af[am], bf[bn], acc[am][bn]);
    __syncthreads();
  }

#pragma unroll
  for (int am = 0; am < 4; ++am) {
#pragma unroll
    for (int bn = 0; bn < 4; ++bn) {
#pragma unroll
      for (int r = 0; r < 4; ++r) {
        const int m = bm * 128 + wm * 64 + am * 16 + lq * 4 + r;  // D row map (HW-verified)
        const int n = bnb * 128 + wn * 64 + bn * 16 + l16;        // D col map
        const float vsum = acc[am][bn][r];
        if (EPI == 0) {
          const int which = n >> 10;           // 0=q 1=k 2=v
          const int nn = n & 1023;
          const int h = nn >> 6, d = nn & 63;
          const int b = m >> 12, s = m & 4095;
          ((u16*)Out)[(size_t)which * 8388608 +
                      (((size_t)(b * NH + h)) * SEQ + s) * DHE + d] = f2h(vsum);
        } else {
          ((float*)Out)[(size_t)m * 1024 + n] = vsum + bias[n];
        }
      }
    }
  }
}

// ---- flash attention --------------------------------------------------------
// grid: bh*32 + qb. 4 waves x 32 q-rows = 128 q-rows/block, KBLK=64.
// Swapped QK^T: lane(l16,lq) reg r holds S[key = k2*16+lq*4+r][q = qh*16+l16].
// Softmax in base-2 domain; deferred max (THR=8 => P<=256, fits fp16);
// row-sums accumulated by MFMA with all-ones B; K/V tile t+1 loads issued early.

__global__ __launch_bounds__(256) void attn_kernel(const u16* __restrict__ Q,
                                                   const u16* __restrict__ K,
                                                   const u16* __restrict__ V,
                                                   const float* __restrict__ logsz,
                                                   u16* __restrict__ Out) {
  __shared__ __align__(16) short Klds[64][72];
  __shared__ __align__(16) short Vtlds[64][72];   // [d][key ^ ((d>>3)<<3)] swizzled

  const int t = threadIdx.x;
  const int bh = blockIdx.x >> 5;   // 32 (B*H)
  const int qb = blockIdx.x & 31;   // 32 q-blocks of 128
  const int lane = t & 63, wv = t >> 6;
  const int l16 = lane & 15, lq = lane >> 4;
  const int b = bh >> 4, h = bh & 15;

  // Q fragments (B operand for swapped QK^T), two 16-row halves per wave
  Frag qf[2][2];
#pragma unroll
  for (int qh = 0; qh < 2; ++qh) {
    const int qrow = qb * 128 + wv * 32 + qh * 16 + l16;
    const u16* qp = Q + ((size_t)bh * SEQ + qrow) * DHE;
#pragma unroll
    for (int f = 0; f < 2; ++f) {
      qf[qh][f].h[0] = *(const short4v*)(qp + f * 32 + lq * 4);
      qf[qh][f].h[1] = *(const short4v*)(qp + f * 32 + lq * 4 + 16);
    }
  }

  Frag ones;
  {
    short4v o1 = {0x3C00, 0x3C00, 0x3C00, 0x3C00};  // fp16 1.0 x4
    ones.h[0] = o1; ones.h[1] = o1;
  }

  float mrow[2] = {-1e30f, -1e30f};
  f32x4 lsum[2];
  f32x4 oacc[2][4];
  f32x4 z = {0.f, 0.f, 0.f, 0.f};
  lsum[0] = z; lsum[1] = z;
#pragma unroll
  for (int qh = 0; qh < 2; ++qh)
#pragma unroll
    for (int d = 0; d < 4; ++d) oacc[qh][d] = z;

  const int a7 = t & 7;
  const int sd = a7 * 8;
  const int skey = t >> 3;        // 0..31
  const int vcol0 = skey ^ (a7 << 3);
  const int vcol1 = (skey + 32) ^ (a7 << 3);

  const u16* Kbase = K + (size_t)bh * SEQ * DHE;
  const u16* Vbase = V + (size_t)bh * SEQ * DHE;
  const float* lbase = logsz + b * SEQ;

  // prologue: stage tile 0 into regs
  uint4 kv0, kv1, vv0, vv1;
  {
    const size_t g0 = (size_t)skey * DHE + sd;
    const size_t g1 = (size_t)(skey + 32) * DHE + sd;
    kv0 = *(const uint4*)(Kbase + g0);
    kv1 = *(const uint4*)(Kbase + g1);
    vv0 = *(const uint4*)(Vbase + g0);
    vv1 = *(const uint4*)(Vbase + g1);
  }

  for (int kt = 0; kt < 64; ++kt) {
    // write staged regs to LDS (K row-major; V transposed + XOR swizzle)
    *(uint4*)&Klds[skey][sd] = kv0;
    *(uint4*)&Klds[skey + 32][sd] = kv1;
    {
      u16 vu[8];
      *(uint4*)vu = vv0;
#pragma unroll
      for (int j = 0; j < 8; ++j) Vtlds[sd + j][vcol0] = (short)vu[j];
      *(uint4*)vu = vv1;
#pragma unroll
      for (int j = 0; j < 8; ++j) Vtlds[sd + j][vcol1] = (short)vu[j];
    }
    __syncthreads();

    // load log2-bias for this tile (keys k2*16+lq*4+r)
    f32x4 lg4[4];
#pragma unroll
    for (int k2 = 0; k2 < 4; ++k2)
      lg4[k2] = *(const f32x4*)(lbase + kt * 64 + k2 * 16 + lq * 4);

    // S^T = K Q^T for both q-halves (K fragments read once)
    f32x4 sc[2][4];
#pragma unroll
    for (int k2 = 0; k2 < 4; ++k2) {
      Frag kfr[2];
#pragma unroll
      for (int f = 0; f < 2; ++f) {
        const short* p = &Klds[k2 * 16 + l16][f * 32 + lq * 4];
        kfr[f].h[0] = *(const short4v*)p;
        kfr[f].h[1] = *(const short4v*)(p + 16);
      }
#pragma unroll
      for (int qh = 0; qh < 2; ++qh) {
        f32x4 a = mfma16(kfr[0], qf[qh][0], z);
        a = mfma16(kfr[1], qf[qh][1], a);
        sc[qh][k2] = a;
      }
    }

    // issue next tile's global loads (latency hides under softmax + PV)
    if (kt < 63) {
      const u16* Kn = Kbase + (size_t)(kt + 1) * 64 * DHE + (size_t)skey * DHE + sd;
      const u16* Vn = Vbase + (size_t)(kt + 1) * 64 * DHE + (size_t)skey * DHE + sd;
      kv0 = *(const uint4*)(Kn);
      kv1 = *(const uint4*)(Kn + 32 * DHE);
      vv0 = *(const uint4*)(Vn);
      vv1 = *(const uint4*)(Vn + 32 * DHE);
    }

    // softmax per q-half (base-2 domain, deferred max)
    Frag paf[2][2];
#pragma unroll
    for (int qh = 0; qh < 2; ++qh) {
      float hm[4];
#pragma unroll
      for (int k2 = 0; k2 < 4; ++k2) {
        f32x4 s = sc[qh][k2] * SCALE2 + lg4[k2];
        sc[qh][k2] = s;
        hm[k2] = fmaxf(fmaxf(s[0], s[1]), fmaxf(s[2], s[3]));
      }
      float mx = fmaxf(fmaxf(hm[0], hm[1]), fmaxf(hm[2], hm[3]));
      mx = fmaxf(mx, __shfl_xor(mx, 16));
      mx = fmaxf(mx, __shfl_xor(mx, 32));
      if (__any(mx > mrow[qh] + 8.f)) {           // wave-uniform rescale (rare)
        const float mn = fmaxf(mrow[qh], mx);
        const float alpha = exp2fast(mrow[qh] - mn);
        mrow[qh] = mn;
        f32x4 alv;
#pragma unroll
        for (int r = 0; r < 4; ++r) alv[r] = __shfl(alpha, lq * 4 + r, 16);
#pragma unroll
        for (int dd = 0; dd < 4; ++dd) oacc[qh][dd] *= alv;
        lsum[qh] *= alv;
      }
      const float m2 = mrow[qh];
#pragma unroll
      for (int k2 = 0; k2 < 4; ++k2) {
        f32x4 s = sc[qh][k2];
#pragma unroll
        for (int r = 0; r < 4; ++r) s[r] = exp2fast(s[r] - m2);
        sc[qh][k2] = s;
      }
      paf[qh][0].h[0] = cvt4(sc[qh][0]); paf[qh][0].h[1] = cvt4(sc[qh][1]);
      paf[qh][1].h[0] = cvt4(sc[qh][2]); paf[qh][1].h[1] = cvt4(sc[qh][3]);
      // row sums via ones-MFMA (owner layout: reg r = q-row lq*4+r)
      lsum[qh] = mfma16(paf[qh][0], ones, lsum[qh]);
      lsum[qh] = mfma16(paf[qh][1], ones, lsum[qh]);
    }

    // O += P V (V fragments read once, used by both q-halves)
#pragma unroll
    for (int dd = 0; dd < 4; ++dd) {
      const int vrow = dd * 16 + l16;
      const int e = ((vrow >> 3) & 7) << 3;
#pragma unroll
      for (int kh = 0; kh < 2; ++kh) {
        Frag vb;
        vb.h[0] = *(const short4v*)&Vtlds[vrow][(kh * 32 + lq * 4) ^ e];
        vb.h[1] = *(const short4v*)&Vtlds[vrow][(kh * 32 + 16 + lq * 4) ^ e];
        oacc[0][dd] = mfma16(paf[0][kh], vb, oacc[0][dd]);
        oacc[1][dd] = mfma16(paf[1][kh], vb, oacc[1][dd]);
      }
    }
    __syncthreads();
  }

  // write attn output merged-head [B][S][C] fp16 (lsum already owner-layout)
#pragma unroll
  for (int qh = 0; qh < 2; ++qh) {
    f32x4 linv;
#pragma unroll
    for (int r = 0; r < 4; ++r) linv[r] = 1.f / lsum[qh][r];
#pragma unroll
    for (int dd = 0; dd < 4; ++dd) {
#pragma unroll
      for (int r = 0; r < 4; ++r) {
        const int row = qb * 128 + wv * 32 + qh * 16 + lq * 4 + r;
        const float v = oacc[qh][dd][r] * linv[r];
        Out[((size_t)b * SEQ + row) * CDIM + h * DHE + dd * 16 + l16] = f2h(v);
      }
    }
  }
}

// ---- launcher ---------------------------------------------------------------

extern "C" void kernel_launch(void* const* d_in, const int* in_sizes, int n_in,
                              void* d_out, int out_size, void* d_ws, size_t ws_size,
                              hipStream_t stream) {
  const float* hs = (const float*)d_in[0];
  const float* Wq = (const float*)d_in[1];
  const float* Wk = (const float*)d_in[2];
  const float* Wv = (const float*)d_in[3];
  const float* Wo = (const float*)d_in[4];
  const float* bo = (const float*)d_in[5];
  const int* ts = (const int*)d_in[6];
  float* out = (float*)d_out;

  char* ws = (char*)d_ws;
  u16* xf = (u16*)(ws);                     // 16,777,216 B; reused as attn_out
  u16* wtq = (u16*)(ws + 16777216);         // q/k/v Wt contiguous -> one N=3072 GEMM
  u16* wtk = (u16*)(ws + 18874368);
  u16* wtv = (u16*)(ws + 20971520);
  u16* wto = (u16*)(ws + 23068672);
  u16* qbuf = (u16*)(ws + 25165824);        // q,k,v contiguous (8,388,608 elems each)
  u16* kbuf = (u16*)(ws + 41943040);
  u16* vbuf = (u16*)(ws + 58720256);
  float* lsz = (float*)(ws + 75497472);

  cast_x_kernel<<<4096, 256, 0, stream>>>(hs, xf);
  transpose_w_kernel<<<4096, 256, 0, stream>>>(Wq, wtq);
  transpose_w_kernel<<<4096, 256, 0, stream>>>(Wk, wtk);
  transpose_w_kernel<<<4096, 256, 0, stream>>>(Wv, wtv);
  transpose_w_kernel<<<4096, 256, 0, stream>>>(Wo, wto);
  logsz_kernel<<<32, 256, 0, stream>>>(ts, lsz);

  // fused QKV projection: A[8192,1024] x Bt[3072,1024]^T
  gemm_f16<0><<<dim3(24, 64), 256, 0, stream>>>(xf, wtq, (void*)qbuf, nullptr);

  attn_kernel<<<1024, 256, 0, stream>>>(qbuf, kbuf, vbuf, lsz, xf);

  // output projection + bias
  gemm_f16<1><<<dim3(8, 64), 256, 0, stream>>>(xf, wto, (void*)out, bo);

  (void)in_sizes; (void)n_in; (void)out_size; (void)ws_size;
}

// Round 5
// 398.828 us; speedup vs baseline: 2.2846x; 1.0133x over previous
//
#include <hip/hip_runtime.h>

// ProportionalAttentionWrapper on MI355X (gfx950), fp16 MFMA pipeline (fp32 accum).
// B=2, S=4096, C=1024, H=16, DH=64. out = softmax(QK^T * 64^0.25 + log(ts)) V, proj.
// R5: V stored transposed globally (GEMM epilogue) -> attn stages V with b128 writes;
// double-buffered K/V LDS (1 barrier/iter); pkrtz P-conversion; tiled W transpose.
// Workspace layout (bytes), total 75,530,240:
//   [0, 16M)            x_fp16 [8192][1024]  (reused as attn_out [B][S][C] fp16)
//   [16M, 24M)          Wt q/k/v/o fp16 [1024][1024] each (q,k,v contiguous => N=3072 GEMM)
//   [24M(25165824), +3*16M) q [bh][s][d], k [bh][s][d], vT [bh][d][s] fp16
//   [75497472, +32KB)   log2(token_sizes) fp32 [B][S]

typedef unsigned short u16;
typedef unsigned int u32;
typedef _Float16 f16x8 __attribute__((ext_vector_type(8)));
typedef float f32x4 __attribute__((ext_vector_type(4)));
typedef short short4v __attribute__((ext_vector_type(4)));

constexpr int SEQ = 4096, CDIM = 1024, NH = 16, DHE = 64;
// 64^0.25 * log2(e): softmax runs in base-2 domain
constexpr float SCALE2 = 2.8284271247461903f * 1.4426950408889634f;

union Frag { f16x8 v; short4v h[2]; };

__device__ __forceinline__ u16 f2h(float f) {
  union { _Float16 h; u16 u; } x;
  x.h = (_Float16)f;  // v_cvt_f16_f32, RNE
  return x.u;
}

__device__ __forceinline__ u32 pkrtz(float a, float b) {
  u32 r;
  asm("v_cvt_pkrtz_f16_f32 %0, %1, %2" : "=v"(r) : "v"(a), "v"(b));
  return r;
}

__device__ __forceinline__ short4v pk4(const f32x4& v) {
  union { u32 w[2]; short4v s; } u;
  u.w[0] = pkrtz(v[0], v[1]);
  u.w[1] = pkrtz(v[2], v[3]);
  return u.s;
}

__device__ __forceinline__ float exp2fast(float x) {
  float r;
  asm("v_exp_f32 %0, %1" : "=v"(r) : "v"(x));
  return r;
}

__device__ __forceinline__ f32x4 mfma16(const Frag& a, const Frag& b, f32x4 c) {
  return __builtin_amdgcn_mfma_f32_16x16x32_f16(a.v, b.v, c, 0, 0, 0);
}

// ---- prep kernels -----------------------------------------------------------

__global__ void cast_x_kernel(const float* __restrict__ x, u16* __restrict__ out) {
  size_t i = ((size_t)blockIdx.x * 256 + threadIdx.x) * 8;
  float4 a = *(const float4*)(x + i);
  float4 b = *(const float4*)(x + i + 4);
  uint4 o;
  o.x = (u32)f2h(a.x) | ((u32)f2h(a.y) << 16);
  o.y = (u32)f2h(a.z) | ((u32)f2h(a.w) << 16);
  o.z = (u32)f2h(b.x) | ((u32)f2h(b.y) << 16);
  o.w = (u32)f2h(b.z) | ((u32)f2h(b.w) << 16);
  *(uint4*)(out + i) = o;
}

// tiled coalesced transpose+cast of all 4 weight matrices (64x64 f32 tiles)
__global__ __launch_bounds__(256) void transpose_w4_kernel(
    const float* __restrict__ Wq, const float* __restrict__ Wk,
    const float* __restrict__ Wv, const float* __restrict__ Wo,
    u16* __restrict__ dq, u16* __restrict__ dk,
    u16* __restrict__ dv, u16* __restrict__ dow) {
  __shared__ float tile[64][65];
  const float* src;
  u16* dst;
  switch (blockIdx.z) {
    case 0: src = Wq; dst = dq; break;
    case 1: src = Wk; dst = dk; break;
    case 2: src = Wv; dst = dv; break;
    default: src = Wo; dst = dow; break;
  }
  const int r0 = blockIdx.y * 64, c0 = blockIdx.x * 64;
  const int tx = threadIdx.x & 63, ty = threadIdx.x >> 6;
#pragma unroll
  for (int i = 0; i < 16; ++i) {
    const int row = i * 4 + ty;
    tile[row][tx] = src[(size_t)(r0 + row) * 1024 + c0 + tx];
  }
  __syncthreads();
#pragma unroll
  for (int i = 0; i < 16; ++i) {
    const int row = i * 4 + ty;
    dst[(size_t)(c0 + row) * 1024 + r0 + tx] = f2h(tile[tx][row]);
  }
}

__global__ void logsz_kernel(const int* __restrict__ ts, float* __restrict__ out) {
  int i = blockIdx.x * 256 + threadIdx.x;
  out[i] = log2f((float)ts[i]);   // base-2 domain bias
}

// ---- GEMM: C[M,N] = A[M,K] * Bt[N,K]^T, M=8192, K=1024 ----------------------
// EPI=0: N=3072, q/k row-major [bh][s][d], v TRANSPOSED [bh][d][s]; EPI=1: fp32 + bias.

template <int EPI>
__global__ __launch_bounds__(256) void gemm_f16(const u16* __restrict__ A,
                                                const u16* __restrict__ Bt,
                                                void* __restrict__ Out,
                                                const float* __restrict__ bias) {
  __shared__ __align__(16) short Alds[128][40];
  __shared__ __align__(16) short Blds[128][40];
  const int t = threadIdx.x;
  const int bnb = blockIdx.x;   // N/128 blocks
  const int bm = blockIdx.y;    // 64
  const int lane = t & 63, wv = t >> 6;
  const int wm = wv >> 1, wn = wv & 1;
  const int l16 = lane & 15, lq = lane >> 4;

  f32x4 acc[4][4];
  f32x4 z = {0.f, 0.f, 0.f, 0.f};
#pragma unroll
  for (int i = 0; i < 4; ++i)
#pragma unroll
    for (int j = 0; j < 4; ++j) acc[i][j] = z;

  const int srow = (t * 8) >> 5;  // staging: 0..63 (+64 on 2nd pass)
  const int scol = (t * 8) & 31;

  for (int kb = 0; kb < 32; ++kb) {
    const int k0 = kb * 32;
#pragma unroll
    for (int i = 0; i < 2; ++i) {
      const int row = srow + i * 64;
      uint4 va = *(const uint4*)(A + (size_t)(bm * 128 + row) * 1024 + k0 + scol);
      *(uint4*)&Alds[row][scol] = va;
      uint4 vb = *(const uint4*)(Bt + (size_t)(bnb * 128 + row) * 1024 + k0 + scol);
      *(uint4*)&Blds[row][scol] = vb;
    }
    __syncthreads();

    Frag af[4], bf[4];
#pragma unroll
    for (int am = 0; am < 4; ++am) {
      const short* p = &Alds[wm * 64 + am * 16 + l16][lq * 4];
      af[am].h[0] = *(const short4v*)p;
      af[am].h[1] = *(const short4v*)(p + 16);
    }
#pragma unroll
    for (int bn = 0; bn < 4; ++bn) {
      const short* p = &Blds[wn * 64 + bn * 16 + l16][lq * 4];
      bf[bn].h[0] = *(const short4v*)p;
      bf[bn].h[1] = *(const short4v*)(p + 16);
    }
#pragma unroll
    for (int am = 0; am < 4; ++am)
#pragma unroll
      for (int bn = 0; bn < 4; ++bn) acc[am][bn] = mfma16(af[am], bf[bn], acc[am][bn]);
    __syncthreads();
  }

#pragma unroll
  for (int am = 0; am < 4; ++am) {
#pragma unroll
    for (int bn = 0; bn < 4; ++bn) {
#pragma unroll
      for (int r = 0; r < 4; ++r) {
        const int m = bm * 128 + wm * 64 + am * 16 + lq * 4 + r;  // D row map (HW-verified)
        const int n = bnb * 128 + wn * 64 + bn * 16 + l16;        // D col map
        const float vsum = acc[am][bn][r];
        if (EPI == 0) {
          const int which = n >> 10;           // 0=q 1=k 2=v
          const int nn = n & 1023;
          const int h = nn >> 6, d = nn & 63;
          const int b = m >> 12, s = m & 4095;
          const int bhh = b * NH + h;
          size_t addr;
          if (which == 2)  // V stored transposed: [bh][d][s]
            addr = (size_t)2 * 8388608 + ((size_t)bhh * DHE + d) * SEQ + s;
          else
            addr = (size_t)which * 8388608 + ((size_t)bhh * SEQ + s) * DHE + d;
          ((u16*)Out)[addr] = f2h(vsum);
        } else {
          ((float*)Out)[(size_t)m * 1024 + n] = vsum + bias[n];
        }
      }
    }
  }
}

// ---- flash attention --------------------------------------------------------
// grid: bh*32 + qb. 4 waves x 32 q-rows = 128 q-rows/block, KBLK=64.
// Swapped QK^T: lane(l16,lq) reg r holds S[key = k2*16+lq*4+r][q = qh*16+l16].
// Softmax base-2, deferred max (THR=8 => P<=256 fits fp16), row-sums via ones-MFMA.
// K/V double-buffered in LDS (1 barrier/iter); V staged from global V^T via b128.

__global__ __launch_bounds__(256) void attn_kernel(const u16* __restrict__ Q,
                                                   const u16* __restrict__ K,
                                                   const u16* __restrict__ Vt,
                                                   const float* __restrict__ logsz,
                                                   u16* __restrict__ Out) {
  __shared__ __align__(16) short Klds[2][64][72];
  __shared__ __align__(16) short Vtlds[2][64][72];  // [d][key ^ ((d>>3)<<3)]

  const int t = threadIdx.x;
  const int bh = blockIdx.x >> 5;   // 32 (B*H)
  const int qb = blockIdx.x & 31;   // 32 q-blocks of 128
  const int lane = t & 63, wv = t >> 6;
  const int l16 = lane & 15, lq = lane >> 4;
  const int b = bh >> 4, h = bh & 15;

  // Q fragments (B operand for swapped QK^T), two 16-row halves per wave
  Frag qf[2][2];
#pragma unroll
  for (int qh = 0; qh < 2; ++qh) {
    const int qrow = qb * 128 + wv * 32 + qh * 16 + l16;
    const u16* qp = Q + ((size_t)bh * SEQ + qrow) * DHE;
#pragma unroll
    for (int f = 0; f < 2; ++f) {
      qf[qh][f].h[0] = *(const short4v*)(qp + f * 32 + lq * 4);
      qf[qh][f].h[1] = *(const short4v*)(qp + f * 32 + lq * 4 + 16);
    }
  }

  Frag ones;
  {
    short4v o1 = {0x3C00, 0x3C00, 0x3C00, 0x3C00};  // fp16 1.0 x4
    ones.h[0] = o1; ones.h[1] = o1;
  }

  float mrow[2] = {-1e30f, -1e30f};
  f32x4 lsum[2];
  f32x4 oacc[2][4];
  f32x4 z = {0.f, 0.f, 0.f, 0.f};
  lsum[0] = z; lsum[1] = z;
#pragma unroll
  for (int qh = 0; qh < 2; ++qh)
#pragma unroll
    for (int d = 0; d < 4; ++d) oacc[qh][d] = z;

  // staging geometry
  const int a7 = t & 7, sd = a7 * 8, skey = t >> 3;      // K: rows skey/skey+32, d-octet sd
  const int vd = t >> 2, voct = (t & 3) * 8;             // V^T: row d=vd, key-octets
  const int vsw = ((vd >> 3) & 7) << 3;                  // XOR swizzle (8-granular)

  const u16* Kbase = K + (size_t)bh * SEQ * DHE;
  const u16* Vtbase = Vt + ((size_t)bh * DHE + vd) * SEQ;
  const float* lbase = logsz + b * SEQ;

  // prologue: stage tile 0 into regs
  uint4 kv0 = *(const uint4*)(Kbase + (size_t)skey * DHE + sd);
  uint4 kv1 = *(const uint4*)(Kbase + (size_t)(skey + 32) * DHE + sd);
  uint4 vv0 = *(const uint4*)(Vtbase + voct);
  uint4 vv1 = *(const uint4*)(Vtbase + voct + 32);

  for (int kt = 0; kt < 64; ++kt) {
    short (*Kb)[72] = Klds[kt & 1];
    short (*Vb)[72] = Vtlds[kt & 1];
    *(uint4*)&Kb[skey][sd] = kv0;
    *(uint4*)&Kb[skey + 32][sd] = kv1;
    *(uint4*)&Vb[vd][voct ^ vsw] = vv0;
    *(uint4*)&Vb[vd][(voct + 32) ^ vsw] = vv1;

    // issue next tile's global loads (complete during compute)
    if (kt < 63) {
      const u16* Kn = Kbase + (size_t)(kt + 1) * 64 * DHE + (size_t)skey * DHE + sd;
      kv0 = *(const uint4*)(Kn);
      kv1 = *(const uint4*)(Kn + 32 * DHE);
      const u16* Vn = Vtbase + (kt + 1) * 64 + voct;
      vv0 = *(const uint4*)(Vn);
      vv1 = *(const uint4*)(Vn + 32);
    }
    __syncthreads();   // single barrier per iter (double-buffered)

    // load log2-bias for this tile (keys k2*16+lq*4+r)
    f32x4 lg4[4];
#pragma unroll
    for (int k2 = 0; k2 < 4; ++k2)
      lg4[k2] = *(const f32x4*)(lbase + kt * 64 + k2 * 16 + lq * 4);

    // S^T = K Q^T for both q-halves (K fragments read once)
    f32x4 sc[2][4];
#pragma unroll
    for (int k2 = 0; k2 < 4; ++k2) {
      Frag kfr[2];
#pragma unroll
      for (int f = 0; f < 2; ++f) {
        const short* p = &Kb[k2 * 16 + l16][f * 32 + lq * 4];
        kfr[f].h[0] = *(const short4v*)p;
        kfr[f].h[1] = *(const short4v*)(p + 16);
      }
#pragma unroll
      for (int qh = 0; qh < 2; ++qh) {
        f32x4 a = mfma16(kfr[0], qf[qh][0], z);
        a = mfma16(kfr[1], qf[qh][1], a);
        sc[qh][k2] = a;
      }
    }

    // softmax per q-half (base-2 domain, deferred max)
    Frag paf[2][2];
#pragma unroll
    for (int qh = 0; qh < 2; ++qh) {
      float hm[4];
#pragma unroll
      for (int k2 = 0; k2 < 4; ++k2) {
        f32x4 s = sc[qh][k2] * SCALE2 + lg4[k2];
        sc[qh][k2] = s;
        hm[k2] = fmaxf(fmaxf(s[0], s[1]), fmaxf(s[2], s[3]));
      }
      float mx = fmaxf(fmaxf(hm[0], hm[1]), fmaxf(hm[2], hm[3]));
      mx = fmaxf(mx, __shfl_xor(mx, 16));
      mx = fmaxf(mx, __shfl_xor(mx, 32));
      if (__any(mx > mrow[qh] + 8.f)) {           // wave-uniform rescale (rare)
        const float mn = fmaxf(mrow[qh], mx);
        const float alpha = exp2fast(mrow[qh] - mn);
        mrow[qh] = mn;
        f32x4 alv;
#pragma unroll
        for (int r = 0; r < 4; ++r) alv[r] = __shfl(alpha, lq * 4 + r, 16);
#pragma unroll
        for (int dd = 0; dd < 4; ++dd) oacc[qh][dd] *= alv;
        lsum[qh] *= alv;
      }
      const float m2 = mrow[qh];
#pragma unroll
      for (int k2 = 0; k2 < 4; ++k2) {
        f32x4 s = sc[qh][k2];
#pragma unroll
        for (int r = 0; r < 4; ++r) s[r] = exp2fast(s[r] - m2);
        sc[qh][k2] = s;
      }
      paf[qh][0].h[0] = pk4(sc[qh][0]); paf[qh][0].h[1] = pk4(sc[qh][1]);
      paf[qh][1].h[0] = pk4(sc[qh][2]); paf[qh][1].h[1] = pk4(sc[qh][3]);
      // row sums via ones-MFMA (owner layout: reg r = q-row lq*4+r)
      lsum[qh] = mfma16(paf[qh][0], ones, lsum[qh]);
      lsum[qh] = mfma16(paf[qh][1], ones, lsum[qh]);
    }

    // O += P V (V fragments read once, used by both q-halves)
#pragma unroll
    for (int dd = 0; dd < 4; ++dd) {
      const int vrow = dd * 16 + l16;
      const int e = ((vrow >> 3) & 7) << 3;
#pragma unroll
      for (int kh = 0; kh < 2; ++kh) {
        Frag vb;
        vb.h[0] = *(const short4v*)&Vb[vrow][(kh * 32 + lq * 4) ^ e];
        vb.h[1] = *(const short4v*)&Vb[vrow][(kh * 32 + 16 + lq * 4) ^ e];
        oacc[0][dd] = mfma16(paf[0][kh], vb, oacc[0][dd]);
        oacc[1][dd] = mfma16(paf[1][kh], vb, oacc[1][dd]);
      }
    }
  }

  // write attn output merged-head [B][S][C] fp16 (lsum already owner-layout)
#pragma unroll
  for (int qh = 0; qh < 2; ++qh) {
    f32x4 linv;
#pragma unroll
    for (int r = 0; r < 4; ++r) linv[r] = 1.f / lsum[qh][r];
#pragma unroll
    for (int dd = 0; dd < 4; ++dd) {
#pragma unroll
      for (int r = 0; r < 4; ++r) {
        const int row = qb * 128 + wv * 32 + qh * 16 + lq * 4 + r;
        const float v = oacc[qh][dd][r] * linv[r];
        Out[((size_t)b * SEQ + row) * CDIM + h * DHE + dd * 16 + l16] = f2h(v);
      }
    }
  }
}

// ---- launcher ---------------------------------------------------------------

extern "C" void kernel_launch(void* const* d_in, const int* in_sizes, int n_in,
                              void* d_out, int out_size, void* d_ws, size_t ws_size,
                              hipStream_t stream) {
  const float* hs = (const float*)d_in[0];
  const float* Wq = (const float*)d_in[1];
  const float* Wk = (const float*)d_in[2];
  const float* Wv = (const float*)d_in[3];
  const float* Wo = (const float*)d_in[4];
  const float* bo = (const float*)d_in[5];
  const int* ts = (const int*)d_in[6];
  float* out = (float*)d_out;

  char* ws = (char*)d_ws;
  u16* xf = (u16*)(ws);                     // 16,777,216 B; reused as attn_out
  u16* wtq = (u16*)(ws + 16777216);         // q/k/v Wt contiguous -> one N=3072 GEMM
  u16* wtk = (u16*)(ws + 18874368);
  u16* wtv = (u16*)(ws + 20971520);
  u16* wto = (u16*)(ws + 23068672);
  u16* qbuf = (u16*)(ws + 25165824);        // q,k,vT contiguous (8,388,608 elems each)
  u16* kbuf = (u16*)(ws + 41943040);
  u16* vtbuf = (u16*)(ws + 58720256);       // V^T [bh][d][s]
  float* lsz = (float*)(ws + 75497472);

  cast_x_kernel<<<4096, 256, 0, stream>>>(hs, xf);
  transpose_w4_kernel<<<dim3(16, 16, 4), 256, 0, stream>>>(Wq, Wk, Wv, Wo,
                                                           wtq, wtk, wtv, wto);
  logsz_kernel<<<32, 256, 0, stream>>>(ts, lsz);

  // fused QKV projection: A[8192,1024] x Bt[3072,1024]^T (V written transposed)
  gemm_f16<0><<<dim3(24, 64), 256, 0, stream>>>(xf, wtq, (void*)qbuf, nullptr);

  attn_kernel<<<1024, 256, 0, stream>>>(qbuf, kbuf, vtbuf, lsz, xf);

  // output projection + bias
  gemm_f16<1><<<dim3(8, 64), 256, 0, stream>>>(xf, wto, (void*)out, bo);

  (void)in_sizes; (void)n_in; (void)out_size; (void)ws_size;
}